// Round 7
// baseline (274.924 us; speedup 1.0000x reference)
//
#include <hip/hip_runtime.h>

#define NB   8192
#define HW   4096   // 64*64

typedef float vfloat4 __attribute__((ext_vector_type(4)));  // native vec for nt-load

// Single fused kernel. One 64-lane wave per sample; 4 waves/block; grid NB/4
// (= 8192 waves = exactly one full-occupancy round on 256 CUs).
// All 16 float4 loads are NONTEMPORAL and issued back-to-back (max MLP,
// no cache allocation for the zero-reuse 134 MB stream). Accumulates
//   s0 = sum x, sj = sum j*x, sk = sum k*x, sq = sum (j^2+k^2)*x
// plus first-max argmax (strict '>', increasing per-lane scan order).
// Wave shuffle reduce -> lane 0 writes closed-form per-sample loss
//   loss = (mx^2+my^2)*s0 - 2*mx*sj - 2*my*sk + sq
// to ws[b]. Last block (atomic counter, zeroed by a memset node) reduces
// the 8192 partials in a fixed order -> bitwise deterministic.
__global__ __launch_bounds__(256) void fused_loss(const float* __restrict__ x,
                                                  float* __restrict__ ws,
                                                  unsigned* __restrict__ counter,
                                                  float* __restrict__ out) {
    const int t    = threadIdx.x;
    const int lane = t & 63;
    const int wave = t >> 6;
    const int b    = blockIdx.x * 4 + wave;

    const vfloat4* xp = (const vfloat4*)(x + (size_t)b * HW) + lane;

    // Stage the whole sample: 16 independent nontemporal 16B loads.
    vfloat4 r[16];
#pragma unroll
    for (int it = 0; it < 16; ++it)
        r[it] = __builtin_nontemporal_load(xp + it * 64);

    // e = it*256 + 4*lane + c :
    //   j = e>>6 = 4*it + (lane>>4)   (same for all 4 components of a float4)
    //   k = e&63 = 4*(lane&15) + c    (independent of it)
    float kf[4], kk[4];
#pragma unroll
    for (int c = 0; c < 4; ++c) {
        kf[c] = (float)(4 * (lane & 15) + c);
        kk[c] = kf[c] * kf[c];
    }

    float jf = (float)(lane >> 4);
    int   eb = 4 * lane;              // flat index of component 0 at iter 0

    float s0 = 0.f, sj = 0.f, sk = 0.f, sq = 0.f;
    float maxv = -__builtin_inff();
    int   maxi = 0;

#pragma unroll
    for (int it = 0; it < 16; ++it) {
        const float jj = jf * jf;
        const vfloat4 v4 = r[it];
#pragma unroll
        for (int c = 0; c < 4; ++c) {
            const float v = v4[c];
            s0 += v;
            sj = fmaf(jf, v, sj);
            sk = fmaf(kf[c], v, sk);
            sq = fmaf(jj + kk[c], v, sq);
            const bool gt = v > maxv;   // strict '>' => first max per lane
            maxv = gt ? v : maxv;
            maxi = gt ? eb + c : maxi;
        }
        jf += 4.0f;
        eb += 256;
    }

    // Wave reduce (64 lanes); ties -> smaller flat index (first max).
#pragma unroll
    for (int off = 32; off > 0; off >>= 1) {
        s0 += __shfl_down(s0, off);
        sj += __shfl_down(sj, off);
        sk += __shfl_down(sk, off);
        sq += __shfl_down(sq, off);
        const float ov = __shfl_down(maxv, off);
        const int   oi = __shfl_down(maxi, off);
        const bool take = (ov > maxv) || (ov == maxv && oi < maxi);
        maxv = take ? ov : maxv;
        maxi = take ? oi : maxi;
    }

    if (lane == 0) {
        const float mx = (float)(maxi >> 6);
        const float my = (float)(maxi & 63);
        ws[b] = (mx * mx + my * my) * s0 - 2.f * mx * sj - 2.f * my * sk + sq;
    }

    // ---- last-block final reduction (fixed order => deterministic) ----
    __shared__ bool amLast;
    __syncthreads();                       // all 4 waves' ws[b] stores issued
    if (t == 0) {
        __threadfence();                   // release: make ws[b] visible
        const unsigned old = atomicAdd(counter, 1u);
        amLast = (old == (unsigned)(gridDim.x - 1));
    }
    __syncthreads();
    if (amLast) {
        __threadfence();                   // acquire: see all blocks' ws
        float s = 0.f;
#pragma unroll
        for (int i = 0; i < NB / 256; ++i) s += ws[i * 256 + t];
#pragma unroll
        for (int off = 32; off > 0; off >>= 1) s += __shfl_down(s, off);
        __shared__ float l[4];
        if ((t & 63) == 0) l[t >> 6] = s;
        __syncthreads();
        if (t == 0) out[0] = l[0] + l[1] + l[2] + l[3];
    }
}

extern "C" void kernel_launch(void* const* d_in, const int* in_sizes, int n_in,
                              void* d_out, int out_size, void* d_ws, size_t ws_size,
                              hipStream_t stream) {
    const float* x = (const float*)d_in[0];
    float* out = (float*)d_out;
    float* ws  = (float*)d_ws;                       // NB floats of partials
    unsigned* counter = (unsigned*)(ws + NB);        // 4-byte block counter

    hipMemsetAsync(counter, 0, sizeof(unsigned), stream);  // capture-legal
    fused_loss<<<NB / 4, 256, 0, stream>>>(x, ws, counter, out);
}

// Round 8
// 177.013 us; speedup vs baseline: 1.5531x; 1.5531x over previous
//
#include <hip/hip_runtime.h>

#define NB   8192
#define HW   4096   // 64*64

typedef float vfloat4 __attribute__((ext_vector_type(4)));  // native vec for nt-load

// One 64-lane wave per sample; 4 waves (256 thr) per block; grid = NB/4.
// Loads are NONTEMPORAL (zero-reuse 134 MB stream -> no cache allocation)
// with a DEPTH-8 explicit register ring prefetch: load of chunk it+8 is
// issued before chunk it is consumed, so the scheduler cannot collapse the
// loads into a dependent chain (R7 showed it does exactly that for
// plain register-array staging: VGPR=32, 125 us). Accumulates
//   s0 = sum x, sj = sum j*x, sk = sum k*x, sq = sum (j^2+k^2)*x
// plus first-max argmax (strict '>', increasing per-lane scan order).
// Wave shuffle reduce; lane 0 writes the closed-form per-sample loss
//   loss = (mx^2+my^2)*s0 - 2*mx*sj - 2*my*sk + sq
// to ws[b]. Tiny second kernel reduces the 8192 partials (fixed order,
// bitwise deterministic).
__global__ __launch_bounds__(256) void per_sample_loss(const float* __restrict__ x,
                                                       float* __restrict__ ws) {
    const int t    = threadIdx.x;
    const int lane = t & 63;
    const int wave = t >> 6;
    const int b    = blockIdx.x * 4 + wave;

    const vfloat4* xp = (const vfloat4*)(x + (size_t)b * HW) + lane;

    // Depth-8 nontemporal prefetch ring.
    vfloat4 r[8];
#pragma unroll
    for (int p = 0; p < 8; ++p) r[p] = __builtin_nontemporal_load(xp + p * 64);

    // e = it*256 + 4*lane + c :
    //   j = e>>6 = 4*it + (lane>>4)   (same for all 4 components of a float4)
    //   k = e&63 = 4*(lane&15) + c    (independent of it)
    float kf[4], kk[4];
#pragma unroll
    for (int c = 0; c < 4; ++c) {
        kf[c] = (float)(4 * (lane & 15) + c);
        kk[c] = kf[c] * kf[c];
    }

    float jf = (float)(lane >> 4);
    int   eb = 4 * lane;              // flat index of component 0 at iter 0

    float s0 = 0.f, sj = 0.f, sk = 0.f, sq = 0.f;
    float maxv = -__builtin_inff();
    int   maxi = 0;

#pragma unroll
    for (int it = 0; it < 16; ++it) {
        const vfloat4 v4 = r[it & 7];
        if (it + 8 < 16)
            r[it & 7] = __builtin_nontemporal_load(xp + (it + 8) * 64);
        const float jj = jf * jf;
#pragma unroll
        for (int c = 0; c < 4; ++c) {
            const float v = v4[c];
            s0 += v;
            sj = fmaf(jf, v, sj);
            sk = fmaf(kf[c], v, sk);
            sq = fmaf(jj + kk[c], v, sq);
            const bool gt = v > maxv;   // strict '>' => first max per lane
            maxv = gt ? v : maxv;
            maxi = gt ? eb + c : maxi;
        }
        jf += 4.0f;
        eb += 256;
    }

    // Wave reduce (64 lanes); ties -> smaller flat index (first max).
#pragma unroll
    for (int off = 32; off > 0; off >>= 1) {
        s0 += __shfl_down(s0, off);
        sj += __shfl_down(sj, off);
        sk += __shfl_down(sk, off);
        sq += __shfl_down(sq, off);
        const float ov = __shfl_down(maxv, off);
        const int   oi = __shfl_down(maxi, off);
        const bool take = (ov > maxv) || (ov == maxv && oi < maxi);
        maxv = take ? ov : maxv;
        maxi = take ? oi : maxi;
    }

    if (lane == 0) {
        const float mx = (float)(maxi >> 6);
        const float my = (float)(maxi & 63);
        ws[b] = (mx * mx + my * my) * s0 - 2.f * mx * sj - 2.f * my * sk + sq;
    }
}

__global__ __launch_bounds__(256) void final_reduce(const float* __restrict__ ws,
                                                    float* __restrict__ out) {
    const int t = threadIdx.x;
    float s = 0.f;
#pragma unroll
    for (int i = 0; i < NB / 256; ++i) s += ws[i * 256 + t];
#pragma unroll
    for (int off = 32; off > 0; off >>= 1) s += __shfl_down(s, off);
    __shared__ float l[4];
    if ((t & 63) == 0) l[t >> 6] = s;
    __syncthreads();
    if (t == 0) out[0] = l[0] + l[1] + l[2] + l[3];
}

extern "C" void kernel_launch(void* const* d_in, const int* in_sizes, int n_in,
                              void* d_out, int out_size, void* d_ws, size_t ws_size,
                              hipStream_t stream) {
    const float* x = (const float*)d_in[0];
    float* out = (float*)d_out;
    float* ws  = (float*)d_ws;   // 8192 floats = 32 KiB scratch

    per_sample_loss<<<NB / 4, 256, 0, stream>>>(x, ws);
    final_reduce<<<1, 256, 0, stream>>>(ws, out);
}